// Round 1
// baseline (2838.649 us; speedup 1.0000x reference)
//
#include <hip/hip_runtime.h>
#include <math.h>

#define Bdim 512
#define Sdim 512
#define Ddim 1024
#define Cdim 33

// ---------------------------------------------------------------------------
// out[b][c] = b2[c]   (atomicAdd target init; harness poisons d_out each call)
__global__ __launch_bounds__(256) void k_init_out(const float* __restrict__ b2,
                                                  float* __restrict__ out) {
  int i = blockIdx.x * 256 + threadIdx.x;      // grid 66*256 = 16896 exact
  out[i] = b2[i % Cdim];
}

// ---------------------------------------------------------------------------
// scores[b][c][s] = (1/32) * sum_d q[c][d] * x[b][s][d]
// grid (S/128, B), 256 threads. C padded to 48. Thread tile 3 rows x 8 cols.
__global__ __launch_bounds__(256) void k_scores(const float* __restrict__ x,
                                                const float* __restrict__ q,
                                                float* __restrict__ sc) {
  __shared__ float qs[48][36];
  __shared__ float xs[128][36];
  const int s0 = blockIdx.x * 128;
  const int b  = blockIdx.y;
  const int t  = threadIdx.x;
  const int kk = t & 31, lr = t >> 5;   // loader coords
  const int tx = t & 15, ty = t >> 4;   // compute coords (16x16)
  float acc[3][8];
#pragma unroll
  for (int i = 0; i < 3; ++i)
#pragma unroll
    for (int j = 0; j < 8; ++j) acc[i][j] = 0.f;

  const float* xb = x + ((size_t)b * Sdim + s0) * Ddim;

  for (int k0 = 0; k0 < Ddim; k0 += 32) {
#pragma unroll
    for (int p = 0; p < 6; ++p) {
      int r = p * 8 + lr;
      qs[r][kk] = (r < Cdim) ? q[r * Ddim + k0 + kk] : 0.f;
    }
#pragma unroll
    for (int p = 0; p < 16; ++p) {
      int r = p * 8 + lr;
      xs[r][kk] = xb[r * Ddim + k0 + kk];
    }
    __syncthreads();
#pragma unroll
    for (int k = 0; k < 32; k += 4) {
      float av[3][4];
#pragma unroll
      for (int i = 0; i < 3; ++i) {
        float4 v = *(const float4*)&qs[ty * 3 + i][k];
        av[i][0] = v.x; av[i][1] = v.y; av[i][2] = v.z; av[i][3] = v.w;
      }
      float bvv[8][4];
#pragma unroll
      for (int j = 0; j < 8; ++j) {
        float4 v = *(const float4*)&xs[tx + 16 * j][k];
        bvv[j][0] = v.x; bvv[j][1] = v.y; bvv[j][2] = v.z; bvv[j][3] = v.w;
      }
#pragma unroll
      for (int u = 0; u < 4; ++u)
#pragma unroll
        for (int i = 0; i < 3; ++i)
#pragma unroll
          for (int j = 0; j < 8; ++j)
            acc[i][j] = fmaf(av[i][u], bvv[j][u], acc[i][j]);
    }
    __syncthreads();
  }
  const float scale = 0.03125f;  // 1024^-0.5
#pragma unroll
  for (int i = 0; i < 3; ++i) {
    int c = ty * 3 + i;
    if (c < Cdim) {
      float* row = sc + ((size_t)b * Cdim + c) * Sdim + s0;
#pragma unroll
      for (int j = 0; j < 8; ++j) row[tx + 16 * j] = acc[i][j] * scale;
    }
  }
}

// ---------------------------------------------------------------------------
// in-place softmax over last dim of scores (B*C rows of length S)
// wave per row; grid (B*C/4), 256 threads
__global__ __launch_bounds__(256) void k_softmax(float* __restrict__ sc) {
  const int wid  = blockIdx.x * 4 + (threadIdx.x >> 6);
  const int lane = threadIdx.x & 63;
  float* row = sc + (size_t)wid * Sdim;
  float4 v0 = *(float4*)&row[lane * 8];
  float4 v1 = *(float4*)&row[lane * 8 + 4];
  float m = fmaxf(fmaxf(fmaxf(v0.x, v0.y), fmaxf(v0.z, v0.w)),
                  fmaxf(fmaxf(v1.x, v1.y), fmaxf(v1.z, v1.w)));
#pragma unroll
  for (int off = 32; off; off >>= 1) m = fmaxf(m, __shfl_xor(m, off));
  v0.x = expf(v0.x - m); v0.y = expf(v0.y - m);
  v0.z = expf(v0.z - m); v0.w = expf(v0.w - m);
  v1.x = expf(v1.x - m); v1.y = expf(v1.y - m);
  v1.z = expf(v1.z - m); v1.w = expf(v1.w - m);
  float s = v0.x + v0.y + v0.z + v0.w + v1.x + v1.y + v1.z + v1.w;
#pragma unroll
  for (int off = 32; off; off >>= 1) s += __shfl_xor(s, off);
  float inv = 1.f / s;
  v0.x *= inv; v0.y *= inv; v0.z *= inv; v0.w *= inv;
  v1.x *= inv; v1.y *= inv; v1.z *= inv; v1.w *= inv;
  *(float4*)&row[lane * 8]     = v0;
  *(float4*)&row[lane * 8 + 4] = v1;
}

// ---------------------------------------------------------------------------
// att[b][c][d] = sum_s w[b][c][s] * x[b][s][d]
// grid (D/128, B), 256 threads. Same skeleton as k_scores, B-operand [k][n].
__global__ __launch_bounds__(256) void k_attended(const float* __restrict__ x,
                                                  const float* __restrict__ w,
                                                  float* __restrict__ att) {
  __shared__ float as_[48][36];
  __shared__ float xs[32][128];
  const int d0 = blockIdx.x * 128;
  const int b  = blockIdx.y;
  const int t  = threadIdx.x;
  const int kk = t & 31, lr = t >> 5;
  const int tx = t & 15, ty = t >> 4;
  float acc[3][8];
#pragma unroll
  for (int i = 0; i < 3; ++i)
#pragma unroll
    for (int j = 0; j < 8; ++j) acc[i][j] = 0.f;

  const float* wb = w + (size_t)b * Cdim * Sdim;
  const float* xb = x + (size_t)b * Sdim * Ddim + d0;

  for (int k0 = 0; k0 < Sdim; k0 += 32) {
#pragma unroll
    for (int p = 0; p < 6; ++p) {
      int r = p * 8 + lr;
      as_[r][kk] = (r < Cdim) ? wb[r * Sdim + k0 + kk] : 0.f;
    }
#pragma unroll
    for (int p = 0; p < 4; ++p) {
      int idx = p * 256 + t;            // float4 index within 32x128 tile
      int r = idx >> 5, c4 = idx & 31;
      *(float4*)&xs[r][c4 * 4] =
          *(const float4*)&xb[(size_t)(k0 + r) * Ddim + c4 * 4];
    }
    __syncthreads();
#pragma unroll
    for (int k = 0; k < 32; k += 4) {
      float av[3][4];
#pragma unroll
      for (int i = 0; i < 3; ++i) {
        float4 v = *(const float4*)&as_[ty * 3 + i][k];
        av[i][0] = v.x; av[i][1] = v.y; av[i][2] = v.z; av[i][3] = v.w;
      }
      float bvv[4][8];
#pragma unroll
      for (int u = 0; u < 4; ++u)
#pragma unroll
        for (int j = 0; j < 4; ++j) {
          float2 p2 = *(const float2*)&xs[k + u][2 * tx + 32 * j];
          bvv[u][2 * j] = p2.x; bvv[u][2 * j + 1] = p2.y;
        }
#pragma unroll
      for (int u = 0; u < 4; ++u)
#pragma unroll
        for (int i = 0; i < 3; ++i)
#pragma unroll
          for (int j = 0; j < 8; ++j)
            acc[i][j] = fmaf(av[i][u], bvv[u][j], acc[i][j]);
    }
    __syncthreads();
  }
#pragma unroll
  for (int i = 0; i < 3; ++i) {
    int c = ty * 3 + i;
    if (c < Cdim) {
      float* row = att + ((size_t)b * Cdim + c) * Ddim + d0;
#pragma unroll
      for (int j = 0; j < 4; ++j) {
        float2 p2 = make_float2(acc[i][2 * j], acc[i][2 * j + 1]);
        *(float2*)&row[2 * tx + 32 * j] = p2;
      }
    }
  }
}

// ---------------------------------------------------------------------------
// fused LN + MLP + logits: per-(c, n-tile, b-tile) block; atomicAdd partials.
// grid (D/128, B/128, C), 256 threads. Thread tile 8x8 (rows ty+16i, cols 2tx+32j).
__global__ __launch_bounds__(256) void k_mlp(const float* __restrict__ att,
                                             const float* __restrict__ gamma,
                                             const float* __restrict__ beta,
                                             const float* __restrict__ W1,
                                             const float* __restrict__ b1,
                                             const float* __restrict__ W2,
                                             float* __restrict__ out) {
  __shared__ float at[128][36];
  __shared__ float bt_[32][128];
  __shared__ float g_full[Ddim];
  __shared__ float be_full[Ddim];
  __shared__ float mu_l[128], iv_l[128];
  __shared__ float w2_l[128], b1_l[128];

  const int n0 = blockIdx.x * 128;
  const int b0 = blockIdx.y * 128;
  const int c  = blockIdx.z;
  const int t  = threadIdx.x;
  const int tx = t & 15, ty = t >> 4;
  const int lane = t & 63, wv = t >> 6;
  const int kk = t & 31, lr = t >> 5;

  // prologue: gamma/beta full rows, W2/b1 tiles
#pragma unroll
  for (int p = 0; p < 4; ++p) {
    g_full[p * 256 + t]  = gamma[c * Ddim + p * 256 + t];
    be_full[p * 256 + t] = beta[c * Ddim + p * 256 + t];
  }
  if (t < 128) {
    w2_l[t] = W2[c * Ddim + n0 + t];
    b1_l[t] = b1[c * Ddim + n0 + t];
  }

  // phase 1: LN stats, wave per row (4 waves x 32 rows)
  for (int rr = 0; rr < 32; ++rr) {
    int r = wv * 32 + rr;
    const float* row = att + ((size_t)(b0 + r) * Cdim + c) * Ddim;
    float s = 0.f, ss = 0.f;
#pragma unroll
    for (int p = 0; p < 4; ++p) {
      float4 v = *(const float4*)&row[lane * 16 + p * 4];
      s  += v.x + v.y + v.z + v.w;
      ss += v.x * v.x + v.y * v.y + v.z * v.z + v.w * v.w;
    }
#pragma unroll
    for (int off = 32; off; off >>= 1) {
      s  += __shfl_xor(s, off);
      ss += __shfl_xor(ss, off);
    }
    if (lane == 0) {
      float mu  = s * (1.f / 1024.f);
      float var = ss * (1.f / 1024.f) - mu * mu;
      mu_l[r] = mu;
      iv_l[r] = 1.f / sqrtf(var + 1e-5f);
    }
  }
  __syncthreads();

  // phase 2: GEMM h_tile = LN(att) @ W1_tile
  float acc[8][8];
#pragma unroll
  for (int i = 0; i < 8; ++i)
#pragma unroll
    for (int j = 0; j < 8; ++j) acc[i][j] = 0.f;

  for (int k0 = 0; k0 < Ddim; k0 += 32) {
#pragma unroll
    for (int p = 0; p < 16; ++p) {
      int r = p * 8 + lr;
      float v = att[((size_t)(b0 + r) * Cdim + c) * Ddim + k0 + kk];
      at[r][kk] = (v - mu_l[r]) * iv_l[r] * g_full[k0 + kk] + be_full[k0 + kk];
    }
#pragma unroll
    for (int p = 0; p < 4; ++p) {
      int idx = p * 256 + t;
      int r = idx >> 5, c4 = idx & 31;
      *(float4*)&bt_[r][c4 * 4] =
          *(const float4*)&W1[((size_t)c * Ddim + k0 + r) * Ddim + n0 + c4 * 4];
    }
    __syncthreads();
#pragma unroll
    for (int k = 0; k < 32; k += 4) {
      float av[8][4];
#pragma unroll
      for (int i = 0; i < 8; ++i) {
        float4 v = *(const float4*)&at[ty + 16 * i][k];
        av[i][0] = v.x; av[i][1] = v.y; av[i][2] = v.z; av[i][3] = v.w;
      }
      float bvv[4][8];
#pragma unroll
      for (int u = 0; u < 4; ++u)
#pragma unroll
        for (int j = 0; j < 4; ++j) {
          float2 p2 = *(const float2*)&bt_[k + u][2 * tx + 32 * j];
          bvv[u][2 * j] = p2.x; bvv[u][2 * j + 1] = p2.y;
        }
#pragma unroll
      for (int u = 0; u < 4; ++u)
#pragma unroll
        for (int i = 0; i < 8; ++i)
#pragma unroll
          for (int j = 0; j < 8; ++j)
            acc[i][j] = fmaf(av[i][u], bvv[u][j], acc[i][j]);
    }
    __syncthreads();
  }

  // epilogue: bias + exact GELU + W2 partial dot, reduce over tx, atomicAdd
  float pl[8];
#pragma unroll
  for (int i = 0; i < 8; ++i) {
    pl[i] = 0.f;
#pragma unroll
    for (int j = 0; j < 8; ++j) {
      int col = 2 * tx + 32 * (j >> 1) + (j & 1);
      float v = acc[i][j] + b1_l[col];
      float h = 0.5f * v * (1.f + erff(v * 0.70710678118f));
      pl[i] = fmaf(h, w2_l[col], pl[i]);
    }
  }
#pragma unroll
  for (int i = 0; i < 8; ++i) {
    float v = pl[i];
    v += __shfl_xor(v, 1); v += __shfl_xor(v, 2);
    v += __shfl_xor(v, 4); v += __shfl_xor(v, 8);
    if (tx == 0) atomicAdd(&out[(size_t)(b0 + ty + 16 * i) * Cdim + c], v);
  }
}

// ---------------------------------------------------------------------------
extern "C" void kernel_launch(void* const* d_in, const int* in_sizes, int n_in,
                              void* d_out, int out_size, void* d_ws, size_t ws_size,
                              hipStream_t stream) {
  const float* x     = (const float*)d_in[0];
  const float* q     = (const float*)d_in[1];
  const float* gamma = (const float*)d_in[2];
  const float* beta  = (const float*)d_in[3];
  const float* W1    = (const float*)d_in[4];
  const float* b1    = (const float*)d_in[5];
  const float* W2    = (const float*)d_in[6];
  const float* b2    = (const float*)d_in[7];
  float* out = (float*)d_out;

  float* scores = (float*)d_ws;                              // B*C*S = 34.6 MB
  float* att    = scores + (size_t)Bdim * Cdim * Sdim;       // B*C*D = 69.2 MB

  k_init_out<<<66, 256, 0, stream>>>(b2, out);
  k_scores<<<dim3(Sdim / 128, Bdim), 256, 0, stream>>>(x, q, scores);
  k_softmax<<<(Bdim * Cdim) / 4, 256, 0, stream>>>(scores);
  k_attended<<<dim3(Ddim / 128, Bdim), 256, 0, stream>>>(x, scores, att);
  k_mlp<<<dim3(Ddim / 128, Bdim / 128, Cdim), 256, 0, stream>>>(
      att, gamma, beta, W1, b1, W2, out);
}